// Round 13
// baseline (393.004 us; speedup 1.0000x reference)
//
#include <hip/hip_runtime.h>

// out[M,N] = x[M,K] @ W_eff[N,K]^T + bias[N],  W_eff = W + 2.0*(B@A)
// M=8192, N=4096, K=4096, R=16.
// Round 13: consolidation. R11's proven pipeline (best: 257us GEMM) with
// (1) 2-tile unroll via template<int CUR> -> compile-time buffer selects,
// (2) cast_x + prep_w fused into one launch (block-range split).
// Pipeline per K-tile (1-phase-offset reads, verified hazard chain):
//   P1: lgkm0; read a47[cur];            MFMA {a03,b01}(0,0); bar
//   P2: lgkm0; read b23[cur];            MFMA {a47,b01}(4,0); vmcnt0; bar
//   P3: lgkm0; read b01'[nxt]; stageA+2; MFMA {a03,b23}(0,2); bar
//   P4: lgkm0; read a03'[nxt]; stageB+2; MFMA {a47,b23}(4,2); bar
// T1 XCD swizzle, T2 XOR swizzle, T5 setprio.

typedef __attribute__((ext_vector_type(4))) float f32x4;
typedef __attribute__((ext_vector_type(8))) short bf16x8;

__device__ __forceinline__ unsigned short f2bf(float f) {
    unsigned u = __builtin_bit_cast(unsigned, f);
    unsigned r = u + 0x7fffu + ((u >> 16) & 1u);
    return (unsigned short)(r >> 16);
}

__device__ __forceinline__ void gload_lds16(const void* g, void* l) {
    __builtin_amdgcn_global_load_lds(
        (const __attribute__((address_space(1))) void*)g,
        (__attribute__((address_space(3))) void*)l, 16, 0, 0);
}

// ---------- fused prep: blocks [0,castBlocks) cast x; rest build W_eff ----------
__global__ __launch_bounds__(256) void prep_kernel(
    const float* __restrict__ x, unsigned short* __restrict__ xb, int n8,
    const float* __restrict__ W, const float* __restrict__ A,
    const float* __restrict__ Bl, unsigned short* __restrict__ wb,
    int K, float scale, int castBlocks)
{
    __shared__ float Bs[16][16];
    if ((int)blockIdx.x < castBlocks) {
        // ---- cast x (f32 -> bf16), grid-stride, 8 elems/iter ----
        int stride = castBlocks * 256;
        for (int i = blockIdx.x * 256 + threadIdx.x; i < n8; i += stride) {
            size_t base = (size_t)i * 8;
            float4 f0 = *(const float4*)&x[base];
            float4 f1 = *(const float4*)&x[base + 4];
            ushort4 o0, o1;
            o0.x = f2bf(f0.x); o0.y = f2bf(f0.y); o0.z = f2bf(f0.z); o0.w = f2bf(f0.w);
            o1.x = f2bf(f1.x); o1.y = f2bf(f1.y); o1.z = f2bf(f1.z); o1.w = f2bf(f1.w);
            *(ushort4*)&xb[base]     = o0;
            *(ushort4*)&xb[base + 4] = o1;
        }
        return;
    }
    // ---- W_eff = W + scale*(B@A), cast to bf16 ----
    const int b = blockIdx.x - castBlocks;
    const int t = threadIdx.x;
    const int n0 = (b >> 4) * 16;          // 256 n-blocks
    const int k0 = (b & 15) * 256;         // 16 k-blocks
    {
        int nl = t >> 4, r = t & 15;
        Bs[nl][r] = Bl[(size_t)(n0 + nl) * 16 + r];
    }
    __syncthreads();

    const int lane = t & 63;
    const int wv = t >> 6;
    const int k = k0 + lane * 4;

    float4 av[16];
#pragma unroll
    for (int r = 0; r < 16; ++r)
        av[r] = *(const float4*)&A[(size_t)r * K + k];

#pragma unroll
    for (int j = 0; j < 4; ++j) {
        const int nl = wv * 4 + j;
        const int n = n0 + nl;
        float4 w = *(const float4*)&W[(size_t)n * K + k];
        float d0 = 0.f, d1 = 0.f, d2 = 0.f, d3 = 0.f;
#pragma unroll
        for (int r = 0; r < 16; ++r) {
            float bb = Bs[nl][r];
            d0 += bb * av[r].x; d1 += bb * av[r].y;
            d2 += bb * av[r].z; d3 += bb * av[r].w;
        }
        ushort4 o;
        o.x = f2bf(w.x + scale * d0);
        o.y = f2bf(w.y + scale * d1);
        o.z = f2bf(w.z + scale * d2);
        o.w = f2bf(w.w + scale * d3);
        *(ushort4*)&wb[(size_t)n * K + k] = o;
    }
}

// ---------------- 256x256 bf16 GEMM + bias, pipelined (unroll x2) ----------------
// 512 threads = 8 waves (2M x 4N), each wave owns 128x64 output.
// LDS [dbuf][A/B][half][128*64 bf16] = 128 KiB. BK=64, 16x16x32 MFMA.
// Swizzle: byte ^= (row&7)<<4 via pre-swizzled global source + swizzled read.

#define SETPRIO(p) __builtin_amdgcn_s_setprio(p)
#define BARRIER()  __builtin_amdgcn_s_barrier()
#define LGKM0()    asm volatile("s_waitcnt lgkmcnt(0)" ::: "memory")

typedef unsigned short lds_t[2][2][2][8192];

struct GemmCtx {
    const unsigned short* Xb;
    const unsigned short* Wb;
    unsigned gA[2][2], gB[2][2];
    int wave, wr, wch, bro, fr, lo0, lo1;
};

#define ST_A4(buf, ktt)                                                         \
    _Pragma("unroll") for (int h = 0; h < 2; ++h)                               \
    _Pragma("unroll") for (int i = 0; i < 2; ++i)                               \
        gload_lds16(c.Xb + c.gA[h][i] + (ktt) * 64,                             \
                    &lds[buf][0][h][i * 4096 + c.wave * 512]);
#define ST_B4(buf, ktt)                                                         \
    _Pragma("unroll") for (int h = 0; h < 2; ++h)                               \
    _Pragma("unroll") for (int i = 0; i < 2; ++i)                               \
        gload_lds16(c.Wb + c.gB[h][i] + (ktt) * 64,                             \
                    &lds[buf][1][h][i * 4096 + c.wave * 512]);

#define RD_A03(P)                                                               \
    _Pragma("unroll") for (int i = 0; i < 4; ++i) {                             \
        a03[i][0] = *(const bf16x8*)((P) + (i * 16 + c.fr) * 128 + c.lo0);      \
        a03[i][1] = *(const bf16x8*)((P) + (i * 16 + c.fr) * 128 + c.lo1);      \
    }
#define RD_A47(P)                                                               \
    _Pragma("unroll") for (int i = 0; i < 4; ++i) {                             \
        a47[i][0] = *(const bf16x8*)((P) + ((4 + i) * 16 + c.fr) * 128 + c.lo0);\
        a47[i][1] = *(const bf16x8*)((P) + ((4 + i) * 16 + c.fr) * 128 + c.lo1);\
    }
#define RD_B01(P)                                                               \
    _Pragma("unroll") for (int i = 0; i < 2; ++i) {                             \
        b01[i][0] = *(const bf16x8*)((P) + (c.bro + i * 16 + c.fr) * 128 + c.lo0);\
        b01[i][1] = *(const bf16x8*)((P) + (c.bro + i * 16 + c.fr) * 128 + c.lo1);\
    }
#define RD_B23(P)                                                               \
    _Pragma("unroll") for (int i = 0; i < 2; ++i) {                             \
        b23[i][0] = *(const bf16x8*)((P) + (c.bro + (2+i) * 16 + c.fr) * 128 + c.lo0);\
        b23[i][1] = *(const bf16x8*)((P) + (c.bro + (2+i) * 16 + c.fr) * 128 + c.lo1);\
    }

#define MFMA_Q(AV, BV, M0, N0)                                                  \
    _Pragma("unroll") for (int mi = 0; mi < 4; ++mi)                            \
    _Pragma("unroll") for (int ni = 0; ni < 2; ++ni)                            \
    _Pragma("unroll") for (int kk = 0; kk < 2; ++kk)                            \
        acc[(M0) + mi][(N0) + ni] = __builtin_amdgcn_mfma_f32_16x16x32_bf16(    \
            AV[mi][kk], BV[ni][kk], acc[(M0) + mi][(N0) + ni], 0, 0, 0);

template<int CUR>
__device__ __forceinline__ void ktile(
    int kt, int NT, lds_t& lds, const GemmCtx& c,
    f32x4 (&acc)[8][4],
    bf16x8 (&a03)[4][2], bf16x8 (&a47)[4][2],
    bf16x8 (&b01)[2][2], bf16x8 (&b23)[2][2])
{
    const char* pA  = (const char*)&lds[CUR][0][c.wr][0];
    const char* pB  = (const char*)&lds[CUR][1][c.wch][0];
    const char* pA1 = (const char*)&lds[CUR ^ 1][0][c.wr][0];
    const char* pB1 = (const char*)&lds[CUR ^ 1][1][c.wch][0];
    const bool stB = (kt + 1 < NT);
    const bool stA = (kt + 2 < NT);

    // ---- P1: drain prev reads; read a47[cur]; MFMA Q(0,0) ----
    LGKM0();
    RD_A47(pA)
    SETPRIO(1);
    MFMA_Q(a03, b01, 0, 0)
    SETPRIO(0);
    BARRIER();

    // ---- P2: drain a47; read b23[cur]; MFMA Q(4,0); vmcnt(0) ----
    LGKM0();
    RD_B23(pB)
    SETPRIO(1);
    MFMA_Q(a47, b01, 4, 0)
    SETPRIO(0);
    asm volatile("s_waitcnt vmcnt(0)" ::: "memory");  // stages from kt-1 landed
    BARRIER();

    // ---- P3: drain b23; read b01'[nxt]; stage A(kt+2); MFMA Q(0,2) ----
    LGKM0();
    if (stB) { RD_B01(pB1) }
    if (stA) { ST_A4(CUR, kt + 2) }
    SETPRIO(1);
    MFMA_Q(a03, b23, 0, 2)    // last use of a03
    SETPRIO(0);
    BARRIER();

    // ---- P4: drain b01'; read a03'[nxt]; stage B(kt+2); MFMA Q(4,2) ----
    LGKM0();
    if (stB) { RD_A03(pA1) }
    if (stA) { ST_B4(CUR, kt + 2) }
    SETPRIO(1);
    MFMA_Q(a47, b23, 4, 2)    // last use of a47,b23
    SETPRIO(0);
    BARRIER();
}

__global__ __launch_bounds__(512, 2) void gemm256_kernel(
    const unsigned short* __restrict__ Xb, const unsigned short* __restrict__ Wb,
    const float* __restrict__ bias, float* __restrict__ out,
    int M, int N, int K)
{
    __shared__ __align__(16) unsigned short lds[2][2][2][8192];

    const int NT = K / 64;
    const int ntn = N / 256;
    int bid = blockIdx.x;
    {   // XCD swizzle (grid 512, divisible by 8 -> bijective)
        int per = gridDim.x >> 3;
        bid = (bid & 7) * per + (bid >> 3);
    }
    const int tm = bid / ntn, tn = bid % ntn;

    const int t = threadIdx.x;
    const int lane = t & 63;

    GemmCtx c;
    c.Xb = Xb; c.Wb = Wb;
    c.wave = t >> 6;
    c.wr  = c.wave >> 2;
    const int wc = c.wave & 3;
    c.wch = wc >> 1;
    c.bro = (wc & 1) * 64;
    c.fr  = lane & 15;
    const int hi16 = ((lane >> 4) & 3) * 16;
    const int bsw = (c.fr & 7) << 4;
    c.lo0 = hi16 ^ bsw;
    c.lo1 = (64 + hi16) ^ bsw;

    const int srow = t >> 3;
    const int scol = ((t & 7) * 8) ^ (((t >> 3) & 7) << 3);
#pragma unroll
    for (int h = 0; h < 2; ++h)
#pragma unroll
        for (int i = 0; i < 2; ++i) {
            c.gA[h][i] = (unsigned)((tm * 256 + h * 128 + i * 64 + srow) * K + scol);
            c.gB[h][i] = (unsigned)((tn * 256 + h * 128 + i * 64 + srow) * K + scol);
        }

    f32x4 acc[8][4] = {};
    bf16x8 a03[4][2], a47[4][2], b01[2][2], b23[2][2];

    // ---- prologue: tiles 0,1 staged; pre-read a03,b01 of tile0 ----
    ST_A4(0, 0) ST_B4(0, 0)
    ST_A4(1, 1) ST_B4(1, 1)
    asm volatile("s_waitcnt vmcnt(8)" ::: "memory");   // tile0 landed
    BARRIER();
    {
        const char* pA = (const char*)&lds[0][0][c.wr][0];
        const char* pB = (const char*)&lds[0][1][c.wch][0];
        RD_A03(pA)
        RD_B01(pB)
    }

    for (int kt = 0; kt < NT; kt += 2) {
        ktile<0>(kt,     NT, lds, c, acc, a03, a47, b01, b23);
        ktile<1>(kt + 1, NT, lds, c, acc, a03, a47, b01, b23);
    }

    // ---- epilogue: C/D layout col=lane&15, row=(lane>>4)*4+reg ----
    const int row0 = tm * 256 + c.wr * 128 + (lane >> 4) * 4;
    const int col0 = tn * 256 + wc * 64;
#pragma unroll
    for (int ni = 0; ni < 4; ++ni) {
        const int col = col0 + ni * 16 + c.fr;
        const float bv = bias[col];
#pragma unroll
        for (int mi = 0; mi < 8; ++mi) {
            const int row = row0 + mi * 16;
#pragma unroll
            for (int r = 0; r < 4; ++r)
                out[(size_t)(row + r) * N + col] = acc[mi][ni][r] + bv;
        }
    }
}

extern "C" void kernel_launch(void* const* d_in, const int* in_sizes, int n_in,
                              void* d_out, int out_size, void* d_ws, size_t ws_size,
                              hipStream_t stream)
{
    const float* x  = (const float*)d_in[0];
    const float* W  = (const float*)d_in[1];
    const float* b  = (const float*)d_in[2];
    const float* A  = (const float*)d_in[3];
    const float* Bl = (const float*)d_in[4];
    float* out = (float*)d_out;

    const int Dout = in_sizes[2];
    const int Din  = in_sizes[1] / Dout;
    const int M    = in_sizes[0] / Din;

    unsigned short* xb = (unsigned short*)d_ws;
    unsigned short* wb = xb + (size_t)M * Din;

    const int castBlocks = 2048;
    const int prepBlocks = (Din / 256) * (Dout / 16);   // 16 * 256 = 4096
    prep_kernel<<<castBlocks + prepBlocks, 256, 0, stream>>>(
        x, xb, M * Din / 8, W, A, Bl, wb, Din, 2.0f, castBlocks);

    const int grid = (M / 256) * (Dout / 256); // 512
    gemm256_kernel<<<grid, 512, 0, stream>>>(xb, wb, b, out, M, Dout, Din);
}

// Round 14
// 303.404 us; speedup vs baseline: 1.2953x; 1.2953x over previous
//
#include <hip/hip_runtime.h>

// out[M,N] = x[M,K] @ W_eff[N,K]^T + bias[N],  W_eff = W + 2.0*(B@A)
// M=8192, N=4096, K=4096, R=16.
// Round 14: exact R11 pipeline (best: 257us GEMM) + staggered counted vmcnt:
// stage order swapped to B@P3 / A@P4 so that
//   P2: vmcnt(4) drains only B(kt+1) (needed at P3), A still flying
//   P3: vmcnt(4) drains only A(kt+1) (needed at P4), B(kt+2) flying
// -> steady state never drains the VM queue to 0. Separate cast/prep
// launches (R13's fusion caused L3 churn, FETCH +56%). T1/T2/T5 unchanged.

typedef __attribute__((ext_vector_type(4))) float f32x4;
typedef __attribute__((ext_vector_type(8))) short bf16x8;

__device__ __forceinline__ unsigned short f2bf(float f) {
    unsigned u = __builtin_bit_cast(unsigned, f);
    unsigned r = u + 0x7fffu + ((u >> 16) & 1u);
    return (unsigned short)(r >> 16);
}

__device__ __forceinline__ void gload_lds16(const void* g, void* l) {
    __builtin_amdgcn_global_load_lds(
        (const __attribute__((address_space(1))) void*)g,
        (__attribute__((address_space(3))) void*)l, 16, 0, 0);
}

// ---------------- cast x (f32 -> bf16) ----------------
__global__ __launch_bounds__(256) void cast_x_kernel(
    const float* __restrict__ x, unsigned short* __restrict__ xb, int n8)
{
    int stride = gridDim.x * blockDim.x;
    for (int i = blockIdx.x * blockDim.x + threadIdx.x; i < n8; i += stride) {
        size_t base = (size_t)i * 8;
        float4 f0 = *(const float4*)&x[base];
        float4 f1 = *(const float4*)&x[base + 4];
        ushort4 o0, o1;
        o0.x = f2bf(f0.x); o0.y = f2bf(f0.y); o0.z = f2bf(f0.z); o0.w = f2bf(f0.w);
        o1.x = f2bf(f1.x); o1.y = f2bf(f1.y); o1.z = f2bf(f1.z); o1.w = f2bf(f1.w);
        *(ushort4*)&xb[base]     = o0;
        *(ushort4*)&xb[base + 4] = o1;
    }
}

// ------------- W_eff = W + scale*(B@A), cast to bf16 -------------
__global__ __launch_bounds__(256) void prep_w_kernel(
    const float* __restrict__ W, const float* __restrict__ A,
    const float* __restrict__ Bl, unsigned short* __restrict__ wb,
    int K, float scale)
{
    __shared__ float Bs[16][16];
    const int t = threadIdx.x;
    const int n0 = blockIdx.y * 16;
    const int k0 = blockIdx.x * 256;
    {
        int nl = t >> 4, r = t & 15;
        Bs[nl][r] = Bl[(size_t)(n0 + nl) * 16 + r];
    }
    __syncthreads();

    const int lane = t & 63;
    const int wv = t >> 6;
    const int k = k0 + lane * 4;

    float4 av[16];
#pragma unroll
    for (int r = 0; r < 16; ++r)
        av[r] = *(const float4*)&A[(size_t)r * K + k];

#pragma unroll
    for (int j = 0; j < 4; ++j) {
        const int nl = wv * 4 + j;
        const int n = n0 + nl;
        float4 w = *(const float4*)&W[(size_t)n * K + k];
        float d0 = 0.f, d1 = 0.f, d2 = 0.f, d3 = 0.f;
#pragma unroll
        for (int r = 0; r < 16; ++r) {
            float b = Bs[nl][r];
            d0 += b * av[r].x; d1 += b * av[r].y;
            d2 += b * av[r].z; d3 += b * av[r].w;
        }
        ushort4 o;
        o.x = f2bf(w.x + scale * d0);
        o.y = f2bf(w.y + scale * d1);
        o.z = f2bf(w.z + scale * d2);
        o.w = f2bf(w.w + scale * d3);
        *(ushort4*)&wb[(size_t)n * K + k] = o;
    }
}

// ---------------- 256x256 bf16 GEMM + bias, pipelined phases ----------------
// 512 threads = 8 waves (2M x 4N), each wave owns 128x64 output.
// LDS [dbuf][A/B][half][128*64 bf16] = 128 KiB. BK=64, 16x16x32 MFMA.
// Swizzle: byte ^= (row&7)<<4 via pre-swizzled global source + swizzled read.

#define SETPRIO(p) __builtin_amdgcn_s_setprio(p)
#define BARRIER()  __builtin_amdgcn_s_barrier()
#define LGKM0()    asm volatile("s_waitcnt lgkmcnt(0)" ::: "memory")
#define VMCNT(n)   asm volatile("s_waitcnt vmcnt(" #n ")" ::: "memory")

__global__ __launch_bounds__(512, 2) void gemm256_kernel(
    const unsigned short* __restrict__ Xb, const unsigned short* __restrict__ Wb,
    const float* __restrict__ bias, float* __restrict__ out,
    int M, int N, int K)
{
    __shared__ __align__(16) unsigned short lds[2][2][2][8192];

    const int NT = K / 64;
    const int ntn = N / 256;
    int bid = blockIdx.x;
    {   // XCD swizzle (grid 512, divisible by 8 -> bijective)
        int per = gridDim.x >> 3;
        bid = (bid & 7) * per + (bid >> 3);
    }
    const int tm = bid / ntn, tn = bid % ntn;

    const int t = threadIdx.x;
    const int lane = t & 63, wave = t >> 6;
    const int wr = wave >> 2;          // 0..1 -> A half, rows wr*128
    const int wc = wave & 3;           // 0..3 -> cols wc*64
    const int wch = wc >> 1;           // B half
    const int bro = (wc & 1) * 64;     // B row offset within half

    // ---- staging addresses (pre-swizzled global source, linear LDS dest) ----
    const int srow = t >> 3;                                   // 0..63
    const int scol = ((t & 7) * 8) ^ (((t >> 3) & 7) << 3);    // elements
    unsigned gA[2][2], gB[2][2];
#pragma unroll
    for (int h = 0; h < 2; ++h)
#pragma unroll
        for (int i = 0; i < 2; ++i) {
            gA[h][i] = (unsigned)((tm * 256 + h * 128 + i * 64 + srow) * K + scol);
            gB[h][i] = (unsigned)((tn * 256 + h * 128 + i * 64 + srow) * K + scol);
        }

#define ST_A4(buf, ktt)                                                         \
    _Pragma("unroll") for (int h = 0; h < 2; ++h)                               \
    _Pragma("unroll") for (int i = 0; i < 2; ++i)                               \
        gload_lds16(Xb + gA[h][i] + (ktt) * 64,                                 \
                    &lds[buf][0][h][i * 4096 + wave * 512]);
#define ST_B4(buf, ktt)                                                         \
    _Pragma("unroll") for (int h = 0; h < 2; ++h)                               \
    _Pragma("unroll") for (int i = 0; i < 2; ++i)                               \
        gload_lds16(Wb + gB[h][i] + (ktt) * 64,                                 \
                    &lds[buf][1][h][i * 4096 + wave * 512]);

    // ---- fragment read offsets (swizzled), 16x16x32 layout ----
    const int fr = lane & 15;
    const int hi16 = ((lane >> 4) & 3) * 16;       // k-offset bytes within row
    const int bsw = (fr & 7) << 4;
    const int lo0 = hi16 ^ bsw;                    // kk=0
    const int lo1 = (64 + hi16) ^ bsw;             // kk=1

    f32x4 acc[8][4] = {};
    bf16x8 a03[4][2], a47[4][2], b01[2][2], b23[2][2];

#define RD_A03(P)                                                               \
    _Pragma("unroll") for (int i = 0; i < 4; ++i) {                             \
        a03[i][0] = *(const bf16x8*)((P) + (i * 16 + fr) * 128 + lo0);          \
        a03[i][1] = *(const bf16x8*)((P) + (i * 16 + fr) * 128 + lo1);          \
    }
#define RD_A47(P)                                                               \
    _Pragma("unroll") for (int i = 0; i < 4; ++i) {                             \
        a47[i][0] = *(const bf16x8*)((P) + ((4 + i) * 16 + fr) * 128 + lo0);    \
        a47[i][1] = *(const bf16x8*)((P) + ((4 + i) * 16 + fr) * 128 + lo1);    \
    }
#define RD_B01(P)                                                               \
    _Pragma("unroll") for (int i = 0; i < 2; ++i) {                             \
        b01[i][0] = *(const bf16x8*)((P) + (bro + i * 16 + fr) * 128 + lo0);    \
        b01[i][1] = *(const bf16x8*)((P) + (bro + i * 16 + fr) * 128 + lo1);    \
    }
#define RD_B23(P)                                                               \
    _Pragma("unroll") for (int i = 0; i < 2; ++i) {                             \
        b23[i][0] = *(const bf16x8*)((P) + (bro + (2+i) * 16 + fr) * 128 + lo0);\
        b23[i][1] = *(const bf16x8*)((P) + (bro + (2+i) * 16 + fr) * 128 + lo1);\
    }

#define MFMA_Q(AV, BV, M0, N0)                                                  \
    _Pragma("unroll") for (int mi = 0; mi < 4; ++mi)                            \
    _Pragma("unroll") for (int ni = 0; ni < 2; ++ni)                            \
    _Pragma("unroll") for (int kk = 0; kk < 2; ++kk)                            \
        acc[(M0) + mi][(N0) + ni] = __builtin_amdgcn_mfma_f32_16x16x32_bf16(    \
            AV[mi][kk], BV[ni][kk], acc[(M0) + mi][(N0) + ni], 0, 0, 0);

    // ---- prologue: stage B0,A0 -> buf0; B1,A1 -> buf1; pre-read tile0 ----
    ST_B4(0, 0) ST_A4(0, 0)
    ST_B4(1, 1) ST_A4(1, 1)
    VMCNT(8);                       // tile0 landed; B1,A1 flying (B1 older)
    BARRIER();
    {
        const char* pA = (const char*)&lds[0][0][wr][0];
        const char* pB = (const char*)&lds[0][1][wch][0];
        RD_A03(pA)
        RD_B01(pB)
    }

    for (int kt = 0; kt < NT; ++kt) {
        const int cur = kt & 1;
        const char* pA  = (const char*)&lds[cur][0][wr][0];
        const char* pB  = (const char*)&lds[cur][1][wch][0];
        const char* pA1 = (const char*)&lds[cur ^ 1][0][wr][0];
        const char* pB1 = (const char*)&lds[cur ^ 1][1][wch][0];
        const bool stB = (kt + 1 < NT);   // next tile exists
        const bool stA = (kt + 2 < NT);   // tile kt+2 exists

        // ---- P1: drain prev reads; read a47[cur]; MFMA Q(0,0) ----
        LGKM0();
        RD_A47(pA)
        SETPRIO(1);
        MFMA_Q(a03, b01, 0, 0)
        SETPRIO(0);
        BARRIER();

        // ---- P2: drain a47; read b23[cur]; MFMA Q(4,0); vmcnt(4) ----
        LGKM0();
        RD_B23(pB)
        SETPRIO(1);
        MFMA_Q(a47, b01, 4, 0)
        SETPRIO(0);
        // B(kt+1) (oldest 4 outstanding, issued 3 phases back) landed;
        // A(kt+1) may still fly.
        if (stB) { VMCNT(4); } else { VMCNT(0); }
        BARRIER();

        // ---- P3: drain b23; read b01'[nxt]; stage B(kt+2); Q(0,2); vmcnt(4) --
        LGKM0();
        if (stB) { RD_B01(pB1) }
        if (stA) { ST_B4(cur, kt + 2) }
        SETPRIO(1);
        MFMA_Q(a03, b23, 0, 2)    // last use of a03
        SETPRIO(0);
        // A(kt+1) (oldest outstanding) landed; B(kt+2) may fly.
        if (stA) { VMCNT(4); } else { VMCNT(0); }
        BARRIER();

        // ---- P4: drain b01'; read a03'[nxt]; stage A(kt+2); Q(4,2) ----
        LGKM0();
        if (stB) { RD_A03(pA1) }
        if (stA) { ST_A4(cur, kt + 2) }
        SETPRIO(1);
        MFMA_Q(a47, b23, 4, 2)    // last use of a47,b23
        SETPRIO(0);
        BARRIER();
    }

    // ---- epilogue: C/D layout col=lane&15, row=(lane>>4)*4+reg ----
    const int row0 = tm * 256 + wr * 128 + (lane >> 4) * 4;
    const int col0 = tn * 256 + wc * 64;
#pragma unroll
    for (int ni = 0; ni < 4; ++ni) {
        const int col = col0 + ni * 16 + fr;
        const float bv = bias[col];
#pragma unroll
        for (int mi = 0; mi < 8; ++mi) {
            const int row = row0 + mi * 16;
#pragma unroll
            for (int r = 0; r < 4; ++r)
                out[(size_t)(row + r) * N + col] = acc[mi][ni][r] + bv;
        }
    }
}

extern "C" void kernel_launch(void* const* d_in, const int* in_sizes, int n_in,
                              void* d_out, int out_size, void* d_ws, size_t ws_size,
                              hipStream_t stream)
{
    const float* x  = (const float*)d_in[0];
    const float* W  = (const float*)d_in[1];
    const float* b  = (const float*)d_in[2];
    const float* A  = (const float*)d_in[3];
    const float* Bl = (const float*)d_in[4];
    float* out = (float*)d_out;

    const int Dout = in_sizes[2];
    const int Din  = in_sizes[1] / Dout;
    const int M    = in_sizes[0] / Din;

    unsigned short* xb = (unsigned short*)d_ws;
    unsigned short* wb = xb + (size_t)M * Din;

    cast_x_kernel<<<2048, 256, 0, stream>>>(x, xb, M * Din / 8);

    dim3 gw(Din / 256, Dout / 16);
    prep_w_kernel<<<gw, 256, 0, stream>>>(W, A, Bl, wb, Din, 2.0f);

    const int grid = (M / 256) * (Dout / 256); // 512
    gemm256_kernel<<<grid, 512, 0, stream>>>(xb, wb, b, out, M, Dout, Din);
}

// Round 15
// 296.146 us; speedup vs baseline: 1.3271x; 1.0245x over previous
//
#include <hip/hip_runtime.h>

// out[M,N] = x[M,K] @ W_eff[N,K]^T + bias[N],  W_eff = W + 2.0*(B@A)
// M=8192, N=4096, K=4096, R=16.
// Round 15: consolidation on the session champion (R11: GEMM 257us,
// total 301.7us). One change: prep_w launched BEFORE cast_x so xb (64MB,
// read first by GEMM staging) is the freshest L3 content at GEMM start.
// GEMM = R11 verbatim: 1-phase-offset pipeline, per-phase lgkm0,
// stages A(kt+2)@P3 / B(kt+2)@P4, vmcnt(0)@P2 (drains kt-1 stages, issued
// 2-3 phases back), T1 XCD swizzle, T2 XOR swizzle, T5 setprio.

typedef __attribute__((ext_vector_type(4))) float f32x4;
typedef __attribute__((ext_vector_type(8))) short bf16x8;

__device__ __forceinline__ unsigned short f2bf(float f) {
    unsigned u = __builtin_bit_cast(unsigned, f);
    unsigned r = u + 0x7fffu + ((u >> 16) & 1u);
    return (unsigned short)(r >> 16);
}

__device__ __forceinline__ void gload_lds16(const void* g, void* l) {
    __builtin_amdgcn_global_load_lds(
        (const __attribute__((address_space(1))) void*)g,
        (__attribute__((address_space(3))) void*)l, 16, 0, 0);
}

// ---------------- cast x (f32 -> bf16) ----------------
__global__ __launch_bounds__(256) void cast_x_kernel(
    const float* __restrict__ x, unsigned short* __restrict__ xb, int n8)
{
    int stride = gridDim.x * blockDim.x;
    for (int i = blockIdx.x * blockDim.x + threadIdx.x; i < n8; i += stride) {
        size_t base = (size_t)i * 8;
        float4 f0 = *(const float4*)&x[base];
        float4 f1 = *(const float4*)&x[base + 4];
        ushort4 o0, o1;
        o0.x = f2bf(f0.x); o0.y = f2bf(f0.y); o0.z = f2bf(f0.z); o0.w = f2bf(f0.w);
        o1.x = f2bf(f1.x); o1.y = f2bf(f1.y); o1.z = f2bf(f1.z); o1.w = f2bf(f1.w);
        *(ushort4*)&xb[base]     = o0;
        *(ushort4*)&xb[base + 4] = o1;
    }
}

// ------------- W_eff = W + scale*(B@A), cast to bf16 -------------
__global__ __launch_bounds__(256) void prep_w_kernel(
    const float* __restrict__ W, const float* __restrict__ A,
    const float* __restrict__ Bl, unsigned short* __restrict__ wb,
    int K, float scale)
{
    __shared__ float Bs[16][16];
    const int t = threadIdx.x;
    const int n0 = blockIdx.y * 16;
    const int k0 = blockIdx.x * 256;
    {
        int nl = t >> 4, r = t & 15;
        Bs[nl][r] = Bl[(size_t)(n0 + nl) * 16 + r];
    }
    __syncthreads();

    const int lane = t & 63;
    const int wv = t >> 6;
    const int k = k0 + lane * 4;

    float4 av[16];
#pragma unroll
    for (int r = 0; r < 16; ++r)
        av[r] = *(const float4*)&A[(size_t)r * K + k];

#pragma unroll
    for (int j = 0; j < 4; ++j) {
        const int nl = wv * 4 + j;
        const int n = n0 + nl;
        float4 w = *(const float4*)&W[(size_t)n * K + k];
        float d0 = 0.f, d1 = 0.f, d2 = 0.f, d3 = 0.f;
#pragma unroll
        for (int r = 0; r < 16; ++r) {
            float b = Bs[nl][r];
            d0 += b * av[r].x; d1 += b * av[r].y;
            d2 += b * av[r].z; d3 += b * av[r].w;
        }
        ushort4 o;
        o.x = f2bf(w.x + scale * d0);
        o.y = f2bf(w.y + scale * d1);
        o.z = f2bf(w.z + scale * d2);
        o.w = f2bf(w.w + scale * d3);
        *(ushort4*)&wb[(size_t)n * K + k] = o;
    }
}

// ---------------- 256x256 bf16 GEMM + bias, pipelined phases ----------------
// 512 threads = 8 waves (2M x 4N), each wave owns 128x64 output.
// LDS [dbuf][A/B][half][128*64 bf16] = 128 KiB. BK=64, 16x16x32 MFMA.
// Swizzle: byte ^= (row&7)<<4 via pre-swizzled global source + swizzled read.

#define SETPRIO(p) __builtin_amdgcn_s_setprio(p)
#define BARRIER()  __builtin_amdgcn_s_barrier()
#define LGKM0()    asm volatile("s_waitcnt lgkmcnt(0)" ::: "memory")

__global__ __launch_bounds__(512, 2) void gemm256_kernel(
    const unsigned short* __restrict__ Xb, const unsigned short* __restrict__ Wb,
    const float* __restrict__ bias, float* __restrict__ out,
    int M, int N, int K)
{
    __shared__ __align__(16) unsigned short lds[2][2][2][8192];

    const int NT = K / 64;
    const int ntn = N / 256;
    int bid = blockIdx.x;
    {   // XCD swizzle (grid 512, divisible by 8 -> bijective)
        int per = gridDim.x >> 3;
        bid = (bid & 7) * per + (bid >> 3);
    }
    const int tm = bid / ntn, tn = bid % ntn;

    const int t = threadIdx.x;
    const int lane = t & 63, wave = t >> 6;
    const int wr = wave >> 2;          // 0..1 -> A half, rows wr*128
    const int wc = wave & 3;           // 0..3 -> cols wc*64
    const int wch = wc >> 1;           // B half
    const int bro = (wc & 1) * 64;     // B row offset within half

    // ---- staging addresses (pre-swizzled global source, linear LDS dest) ----
    const int srow = t >> 3;                                   // 0..63
    const int scol = ((t & 7) * 8) ^ (((t >> 3) & 7) << 3);    // elements
    unsigned gA[2][2], gB[2][2];
#pragma unroll
    for (int h = 0; h < 2; ++h)
#pragma unroll
        for (int i = 0; i < 2; ++i) {
            gA[h][i] = (unsigned)((tm * 256 + h * 128 + i * 64 + srow) * K + scol);
            gB[h][i] = (unsigned)((tn * 256 + h * 128 + i * 64 + srow) * K + scol);
        }

#define ST_A4(buf, ktt)                                                         \
    _Pragma("unroll") for (int h = 0; h < 2; ++h)                               \
    _Pragma("unroll") for (int i = 0; i < 2; ++i)                               \
        gload_lds16(Xb + gA[h][i] + (ktt) * 64,                                 \
                    &lds[buf][0][h][i * 4096 + wave * 512]);
#define ST_B4(buf, ktt)                                                         \
    _Pragma("unroll") for (int h = 0; h < 2; ++h)                               \
    _Pragma("unroll") for (int i = 0; i < 2; ++i)                               \
        gload_lds16(Wb + gB[h][i] + (ktt) * 64,                                 \
                    &lds[buf][1][h][i * 4096 + wave * 512]);

    // ---- fragment read offsets (swizzled), 16x16x32 layout ----
    const int fr = lane & 15;
    const int hi16 = ((lane >> 4) & 3) * 16;       // k-offset bytes within row
    const int bsw = (fr & 7) << 4;
    const int lo0 = hi16 ^ bsw;                    // kk=0
    const int lo1 = (64 + hi16) ^ bsw;             // kk=1

    f32x4 acc[8][4] = {};
    bf16x8 a03[4][2], a47[4][2], b01[2][2], b23[2][2];

#define RD_A03(P)                                                               \
    _Pragma("unroll") for (int i = 0; i < 4; ++i) {                             \
        a03[i][0] = *(const bf16x8*)((P) + (i * 16 + fr) * 128 + lo0);          \
        a03[i][1] = *(const bf16x8*)((P) + (i * 16 + fr) * 128 + lo1);          \
    }
#define RD_A47(P)                                                               \
    _Pragma("unroll") for (int i = 0; i < 4; ++i) {                             \
        a47[i][0] = *(const bf16x8*)((P) + ((4 + i) * 16 + fr) * 128 + lo0);    \
        a47[i][1] = *(const bf16x8*)((P) + ((4 + i) * 16 + fr) * 128 + lo1);    \
    }
#define RD_B01(P)                                                               \
    _Pragma("unroll") for (int i = 0; i < 2; ++i) {                             \
        b01[i][0] = *(const bf16x8*)((P) + (bro + i * 16 + fr) * 128 + lo0);    \
        b01[i][1] = *(const bf16x8*)((P) + (bro + i * 16 + fr) * 128 + lo1);    \
    }
#define RD_B23(P)                                                               \
    _Pragma("unroll") for (int i = 0; i < 2; ++i) {                             \
        b23[i][0] = *(const bf16x8*)((P) + (bro + (2+i) * 16 + fr) * 128 + lo0);\
        b23[i][1] = *(const bf16x8*)((P) + (bro + (2+i) * 16 + fr) * 128 + lo1);\
    }

#define MFMA_Q(AV, BV, M0, N0)                                                  \
    _Pragma("unroll") for (int mi = 0; mi < 4; ++mi)                            \
    _Pragma("unroll") for (int ni = 0; ni < 2; ++ni)                            \
    _Pragma("unroll") for (int kk = 0; kk < 2; ++kk)                            \
        acc[(M0) + mi][(N0) + ni] = __builtin_amdgcn_mfma_f32_16x16x32_bf16(    \
            AV[mi][kk], BV[ni][kk], acc[(M0) + mi][(N0) + ni], 0, 0, 0);

    // ---- prologue: tiles 0,1 staged; pre-read a03,b01 of tile0 ----
    ST_A4(0, 0) ST_B4(0, 0)
    ST_A4(1, 1) ST_B4(1, 1)
    asm volatile("s_waitcnt vmcnt(8)" ::: "memory");   // tile0 landed
    BARRIER();
    {
        const char* pA = (const char*)&lds[0][0][wr][0];
        const char* pB = (const char*)&lds[0][1][wch][0];
        RD_A03(pA)
        RD_B01(pB)
    }

    for (int kt = 0; kt < NT; ++kt) {
        const int cur = kt & 1;
        const char* pA  = (const char*)&lds[cur][0][wr][0];
        const char* pB  = (const char*)&lds[cur][1][wch][0];
        const char* pA1 = (const char*)&lds[cur ^ 1][0][wr][0];
        const char* pB1 = (const char*)&lds[cur ^ 1][1][wch][0];
        const bool stB = (kt + 1 < NT);   // next tile exists
        const bool stA = (kt + 2 < NT);   // tile kt+2 exists

        // ---- P1: drain P4' reads; read a47[cur]; MFMA Q(0,0) ----
        LGKM0();
        RD_A47(pA)
        SETPRIO(1);
        MFMA_Q(a03, b01, 0, 0)
        SETPRIO(0);
        BARRIER();

        // ---- P2: drain a47; read b23[cur]; MFMA Q(4,0); vmcnt(0) ----
        LGKM0();
        RD_B23(pB)
        SETPRIO(1);
        MFMA_Q(a47, b01, 4, 0)
        SETPRIO(0);
        // drains only A(kt+1)/B(kt+1) staged 2-3 phases ago -> ~free
        asm volatile("s_waitcnt vmcnt(0)" ::: "memory");
        BARRIER();

        // ---- P3: drain b23; read b01'[nxt]; stage A(kt+2); Q(0,2) ----
        LGKM0();
        if (stB) { RD_B01(pB1) }
        if (stA) { ST_A4(cur, kt + 2) }
        SETPRIO(1);
        MFMA_Q(a03, b23, 0, 2)    // last use of a03
        SETPRIO(0);
        BARRIER();

        // ---- P4: drain b01'; read a03'[nxt]; stage B(kt+2); Q(4,2) ----
        LGKM0();
        if (stB) { RD_A03(pA1) }
        if (stA) { ST_B4(cur, kt + 2) }
        SETPRIO(1);
        MFMA_Q(a47, b23, 4, 2)    // last use of a47,b23
        SETPRIO(0);
        BARRIER();
    }

    // ---- epilogue: C/D layout col=lane&15, row=(lane>>4)*4+reg ----
    const int row0 = tm * 256 + wr * 128 + (lane >> 4) * 4;
    const int col0 = tn * 256 + wc * 64;
#pragma unroll
    for (int ni = 0; ni < 4; ++ni) {
        const int col = col0 + ni * 16 + fr;
        const float bv = bias[col];
#pragma unroll
        for (int mi = 0; mi < 8; ++mi) {
            const int row = row0 + mi * 16;
#pragma unroll
            for (int r = 0; r < 4; ++r)
                out[(size_t)(row + r) * N + col] = acc[mi][ni][r] + bv;
        }
    }
}

extern "C" void kernel_launch(void* const* d_in, const int* in_sizes, int n_in,
                              void* d_out, int out_size, void* d_ws, size_t ws_size,
                              hipStream_t stream)
{
    const float* x  = (const float*)d_in[0];
    const float* W  = (const float*)d_in[1];
    const float* b  = (const float*)d_in[2];
    const float* A  = (const float*)d_in[3];
    const float* Bl = (const float*)d_in[4];
    float* out = (float*)d_out;

    const int Dout = in_sizes[2];
    const int Din  = in_sizes[1] / Dout;
    const int M    = in_sizes[0] / Din;

    unsigned short* xb = (unsigned short*)d_ws;
    unsigned short* wb = xb + (size_t)M * Din;

    // prep_w first, cast_x second: xb (read first & most by GEMM staging)
    // is the freshest L3 content when the GEMM starts.
    dim3 gw(Din / 256, Dout / 16);
    prep_w_kernel<<<gw, 256, 0, stream>>>(W, A, Bl, wb, Din, 2.0f);

    cast_x_kernel<<<2048, 256, 0, stream>>>(x, xb, M * Din / 8);

    const int grid = (M / 256) * (Dout / 256); // 512
    gemm256_kernel<<<grid, 512, 0, stream>>>(xb, wb, b, out, M, Dout, Din);
}

// Round 16
// 295.941 us; speedup vs baseline: 1.3280x; 1.0007x over previous
//
#include <hip/hip_runtime.h>

// out[M,N] = x[M,K] @ W_eff[N,K]^T + bias[N],  W_eff = W + 2.0*(B@A)
// M=8192, N=4096, K=4096, R=16.
// Round 16: champion config (R15: 296.1us total, GEMM ~250us, MfmaUtil 49%)
// with one provably-safe wait removal: P4's lgkmcnt(0) dropped (its only
// outstanding reads b01'/a03' feed NEXT tile's P1, whose own lgkm0 covers
// them; P4's MFMA operands a47/b23 were drained at P2/P3; the WAR chain for
// staging buf[cur^1] at P3(kt+1) is protected by P1(kt+1)'s drain).
// Structure: 256x256 tile, BK=64, 8 waves (2Mx4N), dbuf LDS 128KB,
// 1-phase-offset operand prefetch, prep_w before cast_x (xb freshest in L3),
// T1 XCD swizzle, T2 XOR swizzle (0 conflicts), T5 setprio.
// Session ladder: 417 (m97-style) -> 288 (256^2 8-phase) -> 271 (R4 sched)
// -> 257 (R11 offset pipeline) -> 250 (R15 launch order). Closed levers:
// 2 blocks/CU @256^2 register-impossible (256 regs/wave x 16 waves > 2048);
// 128^2 tile pays 3.5x FETCH (R10); 11 schedule variants bracket 44-49%.

typedef __attribute__((ext_vector_type(4))) float f32x4;
typedef __attribute__((ext_vector_type(8))) short bf16x8;

__device__ __forceinline__ unsigned short f2bf(float f) {
    unsigned u = __builtin_bit_cast(unsigned, f);
    unsigned r = u + 0x7fffu + ((u >> 16) & 1u);
    return (unsigned short)(r >> 16);
}

__device__ __forceinline__ void gload_lds16(const void* g, void* l) {
    __builtin_amdgcn_global_load_lds(
        (const __attribute__((address_space(1))) void*)g,
        (__attribute__((address_space(3))) void*)l, 16, 0, 0);
}

// ---------------- cast x (f32 -> bf16) ----------------
__global__ __launch_bounds__(256) void cast_x_kernel(
    const float* __restrict__ x, unsigned short* __restrict__ xb, int n8)
{
    int stride = gridDim.x * blockDim.x;
    for (int i = blockIdx.x * blockDim.x + threadIdx.x; i < n8; i += stride) {
        size_t base = (size_t)i * 8;
        float4 f0 = *(const float4*)&x[base];
        float4 f1 = *(const float4*)&x[base + 4];
        ushort4 o0, o1;
        o0.x = f2bf(f0.x); o0.y = f2bf(f0.y); o0.z = f2bf(f0.z); o0.w = f2bf(f0.w);
        o1.x = f2bf(f1.x); o1.y = f2bf(f1.y); o1.z = f2bf(f1.z); o1.w = f2bf(f1.w);
        *(ushort4*)&xb[base]     = o0;
        *(ushort4*)&xb[base + 4] = o1;
    }
}

// ------------- W_eff = W + scale*(B@A), cast to bf16 -------------
__global__ __launch_bounds__(256) void prep_w_kernel(
    const float* __restrict__ W, const float* __restrict__ A,
    const float* __restrict__ Bl, unsigned short* __restrict__ wb,
    int K, float scale)
{
    __shared__ float Bs[16][16];
    const int t = threadIdx.x;
    const int n0 = blockIdx.y * 16;
    const int k0 = blockIdx.x * 256;
    {
        int nl = t >> 4, r = t & 15;
        Bs[nl][r] = Bl[(size_t)(n0 + nl) * 16 + r];
    }
    __syncthreads();

    const int lane = t & 63;
    const int wv = t >> 6;
    const int k = k0 + lane * 4;

    float4 av[16];
#pragma unroll
    for (int r = 0; r < 16; ++r)
        av[r] = *(const float4*)&A[(size_t)r * K + k];

#pragma unroll
    for (int j = 0; j < 4; ++j) {
        const int nl = wv * 4 + j;
        const int n = n0 + nl;
        float4 w = *(const float4*)&W[(size_t)n * K + k];
        float d0 = 0.f, d1 = 0.f, d2 = 0.f, d3 = 0.f;
#pragma unroll
        for (int r = 0; r < 16; ++r) {
            float b = Bs[nl][r];
            d0 += b * av[r].x; d1 += b * av[r].y;
            d2 += b * av[r].z; d3 += b * av[r].w;
        }
        ushort4 o;
        o.x = f2bf(w.x + scale * d0);
        o.y = f2bf(w.y + scale * d1);
        o.z = f2bf(w.z + scale * d2);
        o.w = f2bf(w.w + scale * d3);
        *(ushort4*)&wb[(size_t)n * K + k] = o;
    }
}

// ---------------- 256x256 bf16 GEMM + bias, pipelined phases ----------------
// 512 threads = 8 waves (2M x 4N), each wave owns 128x64 output.
// LDS [dbuf][A/B][half][128*64 bf16] = 128 KiB. BK=64, 16x16x32 MFMA.
// Swizzle: byte ^= (row&7)<<4 via pre-swizzled global source + swizzled read.

#define SETPRIO(p) __builtin_amdgcn_s_setprio(p)
#define BARRIER()  __builtin_amdgcn_s_barrier()
#define LGKM0()    asm volatile("s_waitcnt lgkmcnt(0)" ::: "memory")

__global__ __launch_bounds__(512, 2) void gemm256_kernel(
    const unsigned short* __restrict__ Xb, const unsigned short* __restrict__ Wb,
    const float* __restrict__ bias, float* __restrict__ out,
    int M, int N, int K)
{
    __shared__ __align__(16) unsigned short lds[2][2][2][8192];

    const int NT = K / 64;
    const int ntn = N / 256;
    int bid = blockIdx.x;
    {   // XCD swizzle (grid 512, divisible by 8 -> bijective)
        int per = gridDim.x >> 3;
        bid = (bid & 7) * per + (bid >> 3);
    }
    const int tm = bid / ntn, tn = bid % ntn;

    const int t = threadIdx.x;
    const int lane = t & 63, wave = t >> 6;
    const int wr = wave >> 2;          // 0..1 -> A half, rows wr*128
    const int wc = wave & 3;           // 0..3 -> cols wc*64
    const int wch = wc >> 1;           // B half
    const int bro = (wc & 1) * 64;     // B row offset within half

    // ---- staging addresses (pre-swizzled global source, linear LDS dest) ----
    const int srow = t >> 3;                                   // 0..63
    const int scol = ((t & 7) * 8) ^ (((t >> 3) & 7) << 3);    // elements
    unsigned gA[2][2], gB[2][2];
#pragma unroll
    for (int h = 0; h < 2; ++h)
#pragma unroll
        for (int i = 0; i < 2; ++i) {
            gA[h][i] = (unsigned)((tm * 256 + h * 128 + i * 64 + srow) * K + scol);
            gB[h][i] = (unsigned)((tn * 256 + h * 128 + i * 64 + srow) * K + scol);
        }

#define ST_A4(buf, ktt)                                                         \
    _Pragma("unroll") for (int h = 0; h < 2; ++h)                               \
    _Pragma("unroll") for (int i = 0; i < 2; ++i)                               \
        gload_lds16(Xb + gA[h][i] + (ktt) * 64,                                 \
                    &lds[buf][0][h][i * 4096 + wave * 512]);
#define ST_B4(buf, ktt)                                                         \
    _Pragma("unroll") for (int h = 0; h < 2; ++h)                               \
    _Pragma("unroll") for (int i = 0; i < 2; ++i)                               \
        gload_lds16(Wb + gB[h][i] + (ktt) * 64,                                 \
                    &lds[buf][1][h][i * 4096 + wave * 512]);

    // ---- fragment read offsets (swizzled), 16x16x32 layout ----
    const int fr = lane & 15;
    const int hi16 = ((lane >> 4) & 3) * 16;       // k-offset bytes within row
    const int bsw = (fr & 7) << 4;
    const int lo0 = hi16 ^ bsw;                    // kk=0
    const int lo1 = (64 + hi16) ^ bsw;             // kk=1

    f32x4 acc[8][4] = {};
    bf16x8 a03[4][2], a47[4][2], b01[2][2], b23[2][2];

#define RD_A03(P)                                                               \
    _Pragma("unroll") for (int i = 0; i < 4; ++i) {                             \
        a03[i][0] = *(const bf16x8*)((P) + (i * 16 + fr) * 128 + lo0);          \
        a03[i][1] = *(const bf16x8*)((P) + (i * 16 + fr) * 128 + lo1);          \
    }
#define RD_A47(P)                                                               \
    _Pragma("unroll") for (int i = 0; i < 4; ++i) {                             \
        a47[i][0] = *(const bf16x8*)((P) + ((4 + i) * 16 + fr) * 128 + lo0);    \
        a47[i][1] = *(const bf16x8*)((P) + ((4 + i) * 16 + fr) * 128 + lo1);    \
    }
#define RD_B01(P)                                                               \
    _Pragma("unroll") for (int i = 0; i < 2; ++i) {                             \
        b01[i][0] = *(const bf16x8*)((P) + (bro + i * 16 + fr) * 128 + lo0);    \
        b01[i][1] = *(const bf16x8*)((P) + (bro + i * 16 + fr) * 128 + lo1);    \
    }
#define RD_B23(P)                                                               \
    _Pragma("unroll") for (int i = 0; i < 2; ++i) {                             \
        b23[i][0] = *(const bf16x8*)((P) + (bro + (2+i) * 16 + fr) * 128 + lo0);\
        b23[i][1] = *(const bf16x8*)((P) + (bro + (2+i) * 16 + fr) * 128 + lo1);\
    }

#define MFMA_Q(AV, BV, M0, N0)                                                  \
    _Pragma("unroll") for (int mi = 0; mi < 4; ++mi)                            \
    _Pragma("unroll") for (int ni = 0; ni < 2; ++ni)                            \
    _Pragma("unroll") for (int kk = 0; kk < 2; ++kk)                            \
        acc[(M0) + mi][(N0) + ni] = __builtin_amdgcn_mfma_f32_16x16x32_bf16(    \
            AV[mi][kk], BV[ni][kk], acc[(M0) + mi][(N0) + ni], 0, 0, 0);

    // ---- prologue: tiles 0,1 staged; pre-read a03,b01 of tile0 ----
    ST_A4(0, 0) ST_B4(0, 0)
    ST_A4(1, 1) ST_B4(1, 1)
    asm volatile("s_waitcnt vmcnt(8)" ::: "memory");   // tile0 landed
    BARRIER();
    {
        const char* pA = (const char*)&lds[0][0][wr][0];
        const char* pB = (const char*)&lds[0][1][wch][0];
        RD_A03(pA)
        RD_B01(pB)
    }

    for (int kt = 0; kt < NT; ++kt) {
        const int cur = kt & 1;
        const char* pA  = (const char*)&lds[cur][0][wr][0];
        const char* pB  = (const char*)&lds[cur][1][wch][0];
        const char* pA1 = (const char*)&lds[cur ^ 1][0][wr][0];
        const char* pB1 = (const char*)&lds[cur ^ 1][1][wch][0];
        const bool stB = (kt + 1 < NT);   // next tile exists
        const bool stA = (kt + 2 < NT);   // tile kt+2 exists

        // ---- P1: drain P3'/P4' reads (b01',a03' — needed NOW); read a47;
        //      MFMA Q(0,0) ----
        LGKM0();
        RD_A47(pA)
        SETPRIO(1);
        MFMA_Q(a03, b01, 0, 0)
        SETPRIO(0);
        BARRIER();

        // ---- P2: drain a47; read b23[cur]; MFMA Q(4,0); vmcnt(0) ----
        LGKM0();
        RD_B23(pB)
        SETPRIO(1);
        MFMA_Q(a47, b01, 4, 0)
        SETPRIO(0);
        // drains only A(kt+1)/B(kt+1) staged 2-3 phases ago -> ~free
        asm volatile("s_waitcnt vmcnt(0)" ::: "memory");
        BARRIER();

        // ---- P3: drain b23; read b01'[nxt]; stage A(kt+2); Q(0,2) ----
        LGKM0();
        if (stB) { RD_B01(pB1) }
        if (stA) { ST_A4(cur, kt + 2) }
        SETPRIO(1);
        MFMA_Q(a03, b23, 0, 2)    // last use of a03
        SETPRIO(0);
        BARRIER();

        // ---- P4: read a03'[nxt]; stage B(kt+2); Q(4,2).
        //      NO lgkm wait: operands a47/b23 drained at P2/P3; the b01'/a03'
        //      reads in flight are drained by next tile's P1 LGKM0 before any
        //      use or any stage into buf[cur^1] (which happens at P3(kt+1)). ----
        if (stB) { RD_A03(pA1) }
        if (stA) { ST_B4(cur, kt + 2) }
        SETPRIO(1);
        MFMA_Q(a47, b23, 4, 2)    // last use of a47,b23
        SETPRIO(0);
        BARRIER();
    }

    // ---- epilogue: C/D layout col=lane&15, row=(lane>>4)*4+reg ----
    const int row0 = tm * 256 + wr * 128 + (lane >> 4) * 4;
    const int col0 = tn * 256 + wc * 64;
#pragma unroll
    for (int ni = 0; ni < 4; ++ni) {
        const int col = col0 + ni * 16 + fr;
        const float bv = bias[col];
#pragma unroll
        for (int mi = 0; mi < 8; ++mi) {
            const int row = row0 + mi * 16;
#pragma unroll
            for (int r = 0; r < 4; ++r)
                out[(size_t)(row + r) * N + col] = acc[mi][ni][r] + bv;
        }
    }
}

extern "C" void kernel_launch(void* const* d_in, const int* in_sizes, int n_in,
                              void* d_out, int out_size, void* d_ws, size_t ws_size,
                              hipStream_t stream)
{
    const float* x  = (const float*)d_in[0];
    const float* W  = (const float*)d_in[1];
    const float* b  = (const float*)d_in[2];
    const float* A  = (const float*)d_in[3];
    const float* Bl = (const float*)d_in[4];
    float* out = (float*)d_out;

    const int Dout = in_sizes[2];
    const int Din  = in_sizes[1] / Dout;
    const int M    = in_sizes[0] / Din;

    unsigned short* xb = (unsigned short*)d_ws;
    unsigned short* wb = xb + (size_t)M * Din;

    // prep_w first, cast_x second: xb (read first & most by GEMM staging)
    // is the freshest L3 content when the GEMM starts.
    dim3 gw(Din / 256, Dout / 16);
    prep_w_kernel<<<gw, 256, 0, stream>>>(W, A, Bl, wb, Din, 2.0f);

    cast_x_kernel<<<2048, 256, 0, stream>>>(x, xb, M * Din / 8);

    const int grid = (M / 256) * (Dout / 256); // 512
    gemm256_kernel<<<grid, 512, 0, stream>>>(xb, wb, b, out, M, Dout, Din);
}